// Round 5
// baseline (202.544 us; speedup 1.0000x reference)
//
#include <hip/hip_runtime.h>
#include <math.h>

#define NQ 12
#define NL 4
#define NA 6
#define BATCH 4096
#define NT 128   // 2 waves; lane = t&63 (wires 0..5), w = t>>6 (wire 6), 5 reg bits (wires 7..11 in P0)

typedef float f2 __attribute__((ext_vector_type(2)));

// HW-verified (R3/R4 end-to-end) packed complex primitives; state/coeff = (re,im) in a VGPR pair.
#define CMUL(d, u, a)  asm("v_pk_mul_f32 %0, %1, %2 op_sel_hi:[0,1]"                 : "=v"(d) : "v"(u), "v"(a))
#define CMACR(d, u, a) asm("v_pk_fma_f32 %0, %1, %2, %0 op_sel_hi:[0,1,1]"           : "+v"(d) : "v"(u), "v"(a))
#define CMACI(d, u, a) asm("v_pk_fma_f32 %0, %1, %2, %0 op_sel:[1,1,0] op_sel_hi:[1,0,1] neg_lo:[1,0,0]" : "+v"(d) : "v"(u), "v"(a))
#define WFENCE() asm volatile("s_waitcnt lgkmcnt(0)" ::: "memory")

#define BFLY(A0, A1, U00, U01, U10, U11) do { \
    f2 _a0 = (A0), _a1 = (A1), _n0, _n1; \
    CMUL (_n0, U00, _a0); CMACI(_n0, U00, _a0); \
    CMACR(_n0, U01, _a1); CMACI(_n0, U01, _a1); \
    CMUL (_n1, U10, _a0); CMACI(_n1, U10, _a0); \
    CMACR(_n1, U11, _a1); CMACI(_n1, U11, _a1); \
    (A0) = _n0; (A1) = _n1; } while (0)

// Layouts (amp index i, 12 bits):
//  P0: i = (lane<<6)|(w<<5)|j   wires 0..5 = lane bits 5..0, wire6 = w, wires 7..11 = j bits 4..0
//  P1: i = (j<<7)|(l0<<6)|(w<<5)|(lane>>1)  wires 0..4 = j bits, wire5 = l0, wire6 = w, wires 7..11 = lane bits 5..1
// Transpose P0<->P1 (involution, wave-local): new st[j'] of lane L = old st[L>>1] of lane (j'<<1)|(L&1).
//
// NOTE R4: __launch_bounds__(128,4) capped VGPRs at 64 -> the 64-VGPR state array
// spilled to scratch (FETCH 7MB / WRITE 14.5MB observed). (128,2) lifts the cap to 256.

__global__ __launch_bounds__(NT, 2) void qdqn_kernel(
    const float* __restrict__ x,       // [BATCH,12]
    const float* __restrict__ weights, // [4,12,3]
    const float* __restrict__ fc_w,    // [6,12]
    const float* __restrict__ fc_b,    // [6]
    float* __restrict__ out)           // [BATCH,6]
{
    __shared__ __align__(16) float tbx[2][64 * 33];  // per-wave transpose halves; aliased by exchange
    __shared__ __align__(16) f2 rotc[NL * NQ][4];    // u00,u01,u10,u11 as (re,im)
    __shared__ float encc[NQ], encs[NQ];
    __shared__ float red[2][NQ];
    __shared__ float qout[NQ];

    const int tix  = threadIdx.x;
    const int lane = tix & 63;
    const int w    = tix >> 6;
    const int b    = blockIdx.x;

    // --- setup: 48 rot matrices (threads 0..47), encoding sincos (threads 64..75) ---
    if (tix < NL * NQ) {
        float phi = weights[tix * 3 + 0];
        float th  = weights[tix * 3 + 1];
        float om  = weights[tix * 3 + 2];
        float sth, cth, sa, ca, sb, cb;
        sincosf(0.5f * th, &sth, &cth);
        sincosf(0.5f * (phi + om), &sa, &ca);
        sincosf(0.5f * (phi - om), &sb, &cb);
        rotc[tix][0] = (f2){ ca * cth, -sa * cth };  // u00
        rotc[tix][1] = (f2){ -cb * sth, -sb * sth }; // u01
        rotc[tix][2] = (f2){ cb * sth, -sb * sth };  // u10
        rotc[tix][3] = (f2){ ca * cth,  sa * cth };  // u11
    } else if (tix >= 64 && tix < 64 + NQ) {
        int q = tix - 64;
        float s, c;
        sincosf(0.5f * x[b * NQ + q], &s, &c);
        encc[q] = c; encs[q] = s;
    }
    __syncthreads();

    // --- RY product state in P0 ---
    f2 st[32];
    {
        float pre = w ? encs[6] : encc[6];
#pragma unroll
        for (int q = 0; q < 6; ++q)
            pre *= ((lane >> (5 - q)) & 1) ? encs[q] : encc[q];
        const float c7 = encc[7],  s7 = encs[7];
        const float c8 = encc[8],  s8 = encs[8];
        const float c9 = encc[9],  s9 = encs[9];
        const float cA = encc[10], sA = encs[10];
        const float cB = encc[11], sB = encs[11];
#pragma unroll
        for (int j = 0; j < 32; ++j) {
            float v = pre;
            v *= (j & 16) ? s7 : c7;
            v *= (j & 8)  ? s8 : c8;
            v *= (j & 4)  ? s9 : c9;
            v *= (j & 2)  ? sA : cA;
            v *= (j & 1)  ? sB : cB;
            st[j] = (f2){ v, 0.0f };
        }
    }

    float* const tb = &tbx[w][0];
    f2*    const xb = (f2*)&tbx[0][0];
    const int prt = tix ^ 64;

#pragma unroll 1
    for (int h = 0; h < 2; ++h) {
        // ================= even layer l = 2h (entry P0, exit P1) =================
        {
            const int gb = (2 * h) * NQ;
            // reg gates wires 7..11 (P0: wire 11-bq <-> j bit bq)
#pragma unroll
            for (int bq = 0; bq < 5; ++bq) {
                const f2 u00 = rotc[gb + 11 - bq][0], u01 = rotc[gb + 11 - bq][1];
                const f2 u10 = rotc[gb + 11 - bq][2], u11 = rotc[gb + 11 - bq][3];
                const int S = 1 << bq;
#pragma unroll
                for (int m = 0; m < 16; ++m) {
                    const int j0 = ((m & ~(S - 1)) << 1) | (m & (S - 1));
                    BFLY(st[j0], st[j0 + S], u00, u01, u10, u11);
                }
            }
            // wave-local transpose P0 -> P1 (x then y)
            WFENCE();
#pragma unroll
            for (int j = 0; j < 32; ++j) tb[lane * 33 + j] = st[j].x;
            WFENCE();
#pragma unroll
            for (int j = 0; j < 32; ++j) st[j].x = tb[((j << 1) | (lane & 1)) * 33 + (lane >> 1)];
            WFENCE();
#pragma unroll
            for (int j = 0; j < 32; ++j) tb[lane * 33 + j] = st[j].y;
            WFENCE();
#pragma unroll
            for (int j = 0; j < 32; ++j) st[j].y = tb[((j << 1) | (lane & 1)) * 33 + (lane >> 1)];
            // reg gates wires 0..4 (P1: wire 4-bq <-> j bit bq)
#pragma unroll
            for (int bq = 0; bq < 5; ++bq) {
                const f2 u00 = rotc[gb + 4 - bq][0], u01 = rotc[gb + 4 - bq][1];
                const f2 u10 = rotc[gb + 4 - bq][2], u11 = rotc[gb + 4 - bq][3];
                const int S = 1 << bq;
#pragma unroll
                for (int m = 0; m < 16; ++m) {
                    const int j0 = ((m & ~(S - 1)) << 1) | (m & (S - 1));
                    BFLY(st[j0], st[j0 + S], u00, u01, u10, u11);
                }
            }
            // shuffle gate wire 5 (lane bit 0)
            {
                const f2 u00 = rotc[gb + 5][0], u01 = rotc[gb + 5][1];
                const f2 u10 = rotc[gb + 5][2], u11 = rotc[gb + 5][3];
                const int bit = lane & 1;
                const f2 ca = bit ? u11 : u00;
                const f2 cb = bit ? u10 : u01;
#pragma unroll
                for (int j = 0; j < 32; ++j) {
                    f2 as = st[j], ap, n;
                    ap.x = __shfl_xor(as.x, 1, 64);
                    ap.y = __shfl_xor(as.y, 1, 64);
                    CMUL(n, ca, as); CMACI(n, ca, as); CMACR(n, cb, ap); CMACI(n, cb, ap);
                    st[j] = n;
                }
            }
            // exchange gate wire 6 (w bit), chunked through shared scratch
            {
                const f2 u00 = rotc[gb + 6][0], u01 = rotc[gb + 6][1];
                const f2 u10 = rotc[gb + 6][2], u11 = rotc[gb + 6][3];
                const f2 ca = w ? u11 : u00;
                const f2 cb = w ? u10 : u01;
#pragma unroll
                for (int c = 0; c < 4; ++c) {
                    __syncthreads();
#pragma unroll
                    for (int k = 0; k < 8; ++k) xb[tix * 9 + k] = st[c * 8 + k];
                    __syncthreads();
#pragma unroll
                    for (int k = 0; k < 8; ++k) {
                        f2 as = st[c * 8 + k];
                        f2 ap = xb[prt * 9 + k];
                        f2 n;
                        CMUL(n, ca, as); CMACI(n, ca, as); CMACR(n, cb, ap); CMACI(n, cb, ap);
                        st[c * 8 + k] = n;
                    }
                }
                __syncthreads();
            }
            // CZ in P1: base = wires(7..10 pairs in lane bits) + (l0&w) + (w&l5); per-j: j-pairs + (j0&l0)
            {
                const int par = __popc(lane & (lane >> 1) & 0x1E)
                              + ((lane & 1) & w) + (w & (lane >> 5) & 1);
                const float base = (par & 1) ? -1.0f : 1.0f;
                const float sOdd = (lane & 1) ? -base : base;  // extra (j&1)&(lane&1) term
#pragma unroll
                for (int j = 0; j < 32; ++j) {
                    float s = (j & 1) ? sOdd : base;
                    if (__popc(j & (j >> 1)) & 1) s = -s;      // compile-time per j
                    st[j] *= s;
                }
            }
        }
        // ================= odd layer l = 2h+1 (entry P1, exit P0) =================
        {
            const int gb = (2 * h + 1) * NQ;
            // reg gates wires 0..4 (P1)
#pragma unroll
            for (int bq = 0; bq < 5; ++bq) {
                const f2 u00 = rotc[gb + 4 - bq][0], u01 = rotc[gb + 4 - bq][1];
                const f2 u10 = rotc[gb + 4 - bq][2], u11 = rotc[gb + 4 - bq][3];
                const int S = 1 << bq;
#pragma unroll
                for (int m = 0; m < 16; ++m) {
                    const int j0 = ((m & ~(S - 1)) << 1) | (m & (S - 1));
                    BFLY(st[j0], st[j0 + S], u00, u01, u10, u11);
                }
            }
            // wave-local transpose P1 -> P0
            WFENCE();
#pragma unroll
            for (int j = 0; j < 32; ++j) tb[lane * 33 + j] = st[j].x;
            WFENCE();
#pragma unroll
            for (int j = 0; j < 32; ++j) st[j].x = tb[((j << 1) | (lane & 1)) * 33 + (lane >> 1)];
            WFENCE();
#pragma unroll
            for (int j = 0; j < 32; ++j) tb[lane * 33 + j] = st[j].y;
            WFENCE();
#pragma unroll
            for (int j = 0; j < 32; ++j) st[j].y = tb[((j << 1) | (lane & 1)) * 33 + (lane >> 1)];
            // reg gates wires 7..11 (P0)
#pragma unroll
            for (int bq = 0; bq < 5; ++bq) {
                const f2 u00 = rotc[gb + 11 - bq][0], u01 = rotc[gb + 11 - bq][1];
                const f2 u10 = rotc[gb + 11 - bq][2], u11 = rotc[gb + 11 - bq][3];
                const int S = 1 << bq;
#pragma unroll
                for (int m = 0; m < 16; ++m) {
                    const int j0 = ((m & ~(S - 1)) << 1) | (m & (S - 1));
                    BFLY(st[j0], st[j0 + S], u00, u01, u10, u11);
                }
            }
            // shuffle gate wire 5
            {
                const f2 u00 = rotc[gb + 5][0], u01 = rotc[gb + 5][1];
                const f2 u10 = rotc[gb + 5][2], u11 = rotc[gb + 5][3];
                const int bit = lane & 1;
                const f2 ca = bit ? u11 : u00;
                const f2 cb = bit ? u10 : u01;
#pragma unroll
                for (int j = 0; j < 32; ++j) {
                    f2 as = st[j], ap, n;
                    ap.x = __shfl_xor(as.x, 1, 64);
                    ap.y = __shfl_xor(as.y, 1, 64);
                    CMUL(n, ca, as); CMACI(n, ca, as); CMACR(n, cb, ap); CMACI(n, cb, ap);
                    st[j] = n;
                }
            }
            // exchange gate wire 6
            {
                const f2 u00 = rotc[gb + 6][0], u01 = rotc[gb + 6][1];
                const f2 u10 = rotc[gb + 6][2], u11 = rotc[gb + 6][3];
                const f2 ca = w ? u11 : u00;
                const f2 cb = w ? u10 : u01;
#pragma unroll
                for (int c = 0; c < 4; ++c) {
                    __syncthreads();
#pragma unroll
                    for (int k = 0; k < 8; ++k) xb[tix * 9 + k] = st[c * 8 + k];
                    __syncthreads();
#pragma unroll
                    for (int k = 0; k < 8; ++k) {
                        f2 as = st[c * 8 + k];
                        f2 ap = xb[prt * 9 + k];
                        f2 n;
                        CMUL(n, ca, as); CMACI(n, ca, as); CMACR(n, cb, ap); CMACI(n, cb, ap);
                        st[c * 8 + k] = n;
                    }
                }
                __syncthreads();
            }
            // CZ in P0: base = all 5 lane pairs + (l0&w); per-j: (w & j4) + j-pairs
            {
                const int par = __popc(lane & (lane >> 1)) + ((lane & 1) & w);
                const float base = (par & 1) ? -1.0f : 1.0f;
                const float sHi = w ? -base : base;  // extra (w & (j>>4)) term for j >= 16
#pragma unroll
                for (int j = 0; j < 32; ++j) {
                    float s = (j & 16) ? sHi : base;
                    if (__popc(j & (j >> 1)) & 1) s = -s;  // compile-time per j
                    st[j] *= s;
                }
            }
        }
    }

    // --- measurement in P0 ---
    float tot = 0.f, m7 = 0.f, m8 = 0.f, m9 = 0.f, m10 = 0.f, m11 = 0.f;
#pragma unroll
    for (int j = 0; j < 32; ++j) {
        const float p = st[j].x * st[j].x + st[j].y * st[j].y;
        tot += p;
        m7  += (j & 16) ? -p : p;
        m8  += (j & 8)  ? -p : p;
        m9  += (j & 4)  ? -p : p;
        m10 += (j & 2)  ? -p : p;
        m11 += (j & 1)  ? -p : p;
    }
    float part[NQ];
#pragma unroll
    for (int q = 0; q < 6; ++q)
        part[q] = ((lane >> (5 - q)) & 1) ? -tot : tot;
    part[6] = w ? -tot : tot;
    part[7] = m7; part[8] = m8; part[9] = m9; part[10] = m10; part[11] = m11;

#pragma unroll
    for (int off = 32; off > 0; off >>= 1) {
#pragma unroll
        for (int q = 0; q < NQ; ++q)
            part[q] += __shfl_down(part[q], off, 64);
    }
    if (lane == 0) {
#pragma unroll
        for (int q = 0; q < NQ; ++q) red[w][q] = part[q];
    }
    __syncthreads();
    if (tix < NQ) qout[tix] = red[0][tix] + red[1][tix];
    __syncthreads();

    if (tix < NA) {
        float acc = fc_b[tix];
#pragma unroll
        for (int q = 0; q < NQ; ++q)
            acc += qout[q] * fc_w[tix * NQ + q];
        out[b * NA + tix] = acc;
    }
}

extern "C" void kernel_launch(void* const* d_in, const int* in_sizes, int n_in,
                              void* d_out, int out_size, void* d_ws, size_t ws_size,
                              hipStream_t stream) {
    const float* x   = (const float*)d_in[0];
    const float* w   = (const float*)d_in[1];
    const float* fcw = (const float*)d_in[2];
    const float* fcb = (const float*)d_in[3];
    qdqn_kernel<<<BATCH, NT, 0, stream>>>(x, w, fcw, fcb, (float*)d_out);
}